// Round 5
// baseline (109.928 us; speedup 1.0000x reference)
//
#include <hip/hip_runtime.h>
#include <hip/hip_bf16.h>

#define S_LEN 2048
#define BH_TOTAL 64
#define D_DIM 64
#define NT 32          // S_LEN / 64 kv tiles

typedef float f32x4 __attribute__((ext_vector_type(4)));
typedef float f32x16 __attribute__((ext_vector_type(16)));
typedef __bf16 bf16x8 __attribute__((ext_vector_type(8)));
typedef unsigned short u16x8 __attribute__((ext_vector_type(8)));
typedef unsigned int u32;
typedef u32 u32x2 __attribute__((ext_vector_type(2)));
typedef u32 u32x4 __attribute__((ext_vector_type(4)));

union BF8 { u32x4 w; u16x8 u; bf16x8 b; };

#if __has_builtin(__builtin_amdgcn_exp2f)
#define EX2(x) __builtin_amdgcn_exp2f(x)
#else
#define EX2(x) exp2f(x)
#endif

__device__ __forceinline__ unsigned short f2b(float f) {
  __bf16 h = (__bf16)f;
  return __builtin_bit_cast(unsigned short, h);
}
__device__ __forceinline__ u32 pk2(float a, float b) {
  return (u32)f2b(a) | ((u32)f2b(b) << 16);
}

// permlane32_swap: returns {r0, r1}: r0 = [x.lanes0-31 | y.lanes0-31],
// r1 = [x.lanes32-63 | y.lanes32-63]  (m214 T12 recipe orientation)
__device__ __forceinline__ u32x2 pl32(u32 x, u32 y) {
#if __has_builtin(__builtin_amdgcn_permlane32_swap)
  return __builtin_amdgcn_permlane32_swap(x, y, false, false);
#else
  u32 xs = (u32)__shfl_xor((int)x, 32);
  u32 ys = (u32)__shfl_xor((int)y, 32);
  int hi = (int)(threadIdx.x & 32);
  u32x2 r;
  r.x = hi ? ys : x;
  r.y = hi ? y : xs;
  return r;
#endif
}

__device__ __forceinline__ void gload16(const unsigned short* g, unsigned short* l) {
  __builtin_amdgcn_global_load_lds(
      (const __attribute__((address_space(1))) unsigned int*)g,
      (__attribute__((address_space(3))) unsigned int*)l, 16, 0, 0);
}

// ---------------- pre-pass 1: K fp32 -> bf16 (flat) ----------------
__global__ __launch_bounds__(256)
void cvt_k(const float* __restrict__ K, unsigned short* __restrict__ Kb) {
  int i = blockIdx.x * 256 + threadIdx.x;
  const f32x4* src = (const f32x4*)K;
  f32x4 a = src[2 * i], b = src[2 * i + 1];
  u16x8 o;
  #pragma unroll
  for (int j = 0; j < 4; ++j) { o[j] = f2b(a[j]); o[j + 4] = f2b(b[j]); }
  ((u16x8*)Kb)[i] = o;
}

// ---------------- pre-pass 2: V fp32 [bh][s][d] -> bf16 Vt [bh][d][s] ----------------
__global__ __launch_bounds__(256)
void tr_v(const float* __restrict__ V, unsigned short* __restrict__ Vt) {
  __shared__ unsigned short T[64][72];
  int bh = blockIdx.x >> 5, t5 = blockIdx.x & 31;
  int s0 = t5 * 64;
  int tid = threadIdx.x;
  {
    int s = tid >> 2, d0 = (tid & 3) * 16;
    const float* src = V + ((size_t)bh * S_LEN + s0 + s) * D_DIM + d0;
    #pragma unroll
    for (int j = 0; j < 16; j += 4) {
      f32x4 x = *(const f32x4*)(src + j);
      #pragma unroll
      for (int q2 = 0; q2 < 4; ++q2) T[d0 + j + q2][s] = f2b(x[q2]);
    }
  }
  __syncthreads();
  {
    int d = tid >> 2, c0 = (tid & 3) * 16;
    unsigned short* dst = Vt + ((size_t)bh * D_DIM + d) * S_LEN + s0 + c0;
    u16x8 o;
    #pragma unroll
    for (int q2 = 0; q2 < 8; ++q2) o[q2] = T[d][c0 + q2];
    *(u16x8*)dst = o;
    #pragma unroll
    for (int q2 = 0; q2 < 8; ++q2) o[q2] = T[d][c0 + 8 + q2];
    *(u16x8*)(dst + 8) = o;
  }
}

// ---------------- main attention: 32x32 MFMA, in-register P, 4 waves x 32q ----------------
// LDS phys layout: phys_byte(row, colbyte) = row*128 + (colbyte ^ ((row&7)<<4))
__global__ __launch_bounds__(256, 4)
void attn_fwd(const float* __restrict__ Q, const unsigned short* __restrict__ Kb,
              const unsigned short* __restrict__ Vt, float* __restrict__ O) {
  const int wg = blockIdx.x;
  const int id = (wg & 7) * 128 + (wg >> 3);   // bijective XCD swizzle (1024 % 8 == 0)
  const int qt = id & 15;                      // 16 q-tiles of 128 rows
  const int bh = id >> 4;

  const int tid = threadIdx.x;
  const int w = tid >> 6;      // 0..3
  const int ln = tid & 63;
  const int l31 = ln & 31;     // q owned by this lane (C col); also frag row selector
  const int h = ln >> 5;       // lane half

  __shared__ __align__(16) unsigned short Ks[2][4096];   // K [kv 64][d 64], swizzled
  __shared__ __align__(16) unsigned short Vs[2][4096];   // V^T [d 64][kv 64], swizzled

  const size_t hbase = (size_t)bh * S_LEN * D_DIM;
  const unsigned short* Kh = Kb + hbase;
  const unsigned short* Vh = Vt + hbase;

  const int q0 = qt * 128 + w * 32;

  // ---- Q B-fragments (32x32x16): lane holds Q[q0+l31][f*16 + h*8 + j], scale folded ----
  BF8 qf[4];
  {
    const float sc = 0.125f * 1.44269504088896f;
    const float* qp = Q + hbase + (size_t)(q0 + l31) * D_DIM + h * 8;
    #pragma unroll
    for (int f = 0; f < 4; ++f) {
      f32x4 a = *(const f32x4*)(qp + f * 16);
      f32x4 b = *(const f32x4*)(qp + f * 16 + 4);
      #pragma unroll
      for (int j = 0; j < 4; ++j) {
        qf[f].u[j]     = f2b(a[j] * sc);
        qf[f].u[j + 4] = f2b(b[j] * sc);
      }
    }
  }

  // ---- staging: wave w stages rows [w*16, w*16+16) of K and of V^T ----
  const int srow = ln >> 3;
  const int scol = ((ln & 7) ^ srow) * 8;        // inverse-swizzled source column
  const unsigned short* ks0 = Kh + (size_t)(w * 16 + srow) * D_DIM + scol;
  const unsigned short* vs0 = Vh + (size_t)(w * 16 + srow) * S_LEN + scol;

  // ---- fragment read offsets: addr = tile*4096 + l31*128 + cx[m] ----
  const int swz = (ln & 7) << 4;
  const int rb = l31 * 128;
  int cx[4];                                     // m*32 + h*16, swizzled
  #pragma unroll
  for (int m = 0; m < 4; ++m) cx[m] = (m * 32 + h * 16) ^ swz;

  f32x16 oa0, oa1;
  #pragma unroll
  for (int j = 0; j < 16; ++j) { oa0[j] = 0.f; oa1[j] = 0.f; }
  float ls = 0.f;

  // prologue: stage tile 0
  gload16(ks0,            &Ks[0][w * 1024]);
  gload16(ks0 + 512,      &Ks[0][w * 1024 + 512]);
  gload16(vs0,            &Vs[0][w * 1024]);
  gload16(vs0 + 8 * S_LEN, &Vs[0][w * 1024 + 512]);
  __syncthreads();

  for (int t = 0; t < NT; ++t) {
    const int cur = t & 1;
    if (t + 1 < NT) {
      const unsigned short* kp = ks0 + (size_t)(t + 1) * 4096;
      const unsigned short* vp = vs0 + (t + 1) * 64;
      gload16(kp,             &Ks[cur ^ 1][w * 1024]);
      gload16(kp + 512,       &Ks[cur ^ 1][w * 1024 + 512]);
      gload16(vp,             &Vs[cur ^ 1][w * 1024]);
      gload16(vp + 8 * S_LEN, &Vs[cur ^ 1][w * 1024 + 512]);
    }

    const char* KsB = (const char*)&Ks[cur][0];
    const char* VsB = (const char*)&Vs[cur][0];

    // ---- S^T = K (Q sc)^T : two 32x32 C-tiles (kt=0,1); q = l31 per lane ----
    f32x16 s0, s1;
    #pragma unroll
    for (int j = 0; j < 16; ++j) { s0[j] = 0.f; s1[j] = 0.f; }
    __builtin_amdgcn_s_setprio(1);
    #pragma unroll
    for (int f = 0; f < 4; ++f) {
      BF8 k0, k1;
      k0.u = *(const u16x8*)(KsB + rb + cx[f]);
      k1.u = *(const u16x8*)(KsB + 4096 + rb + cx[f]);
      s0 = __builtin_amdgcn_mfma_f32_32x32x16_bf16(k0.b, qf[f].b, s0, 0, 0, 0);
      s1 = __builtin_amdgcn_mfma_f32_32x32x16_bf16(k1.b, qf[f].b, s1, 0, 0, 0);
    }
    __builtin_amdgcn_s_setprio(0);

    // ---- per kt: p = exp2(s); l-sum; pack; permlane -> P^T B-frags; PV MFMA ----
    #pragma unroll
    for (int kt = 0; kt < 2; ++kt) {
      const f32x16 sv = kt ? s1 : s0;
      float p[16];
      #pragma unroll
      for (int j = 0; j < 16; ++j) p[j] = EX2(sv[j]);
      ls += (((p[0] + p[1]) + (p[2] + p[3])) + ((p[4] + p[5]) + (p[6] + p[7])))
          + (((p[8] + p[9]) + (p[10] + p[11])) + ((p[12] + p[13]) + (p[14] + p[15])));
      u32 wlo[4], whi[4];
      #pragma unroll
      for (int b2 = 0; b2 < 4; ++b2) {
        wlo[b2] = pk2(p[4 * b2 + 0], p[4 * b2 + 1]);   // k = 8*b2 + 4h + {0,1}
        whi[b2] = pk2(p[4 * b2 + 2], p[4 * b2 + 3]);   // k = 8*b2 + 4h + {2,3}
      }
      #pragma unroll
      for (int s = 0; s < 2; ++s) {
        u32x2 rlo = pl32(wlo[2 * s], wlo[2 * s + 1]);  // -> frag words j={0,1}, j={4,5}
        u32x2 rhi = pl32(whi[2 * s], whi[2 * s + 1]);  // -> frag words j={2,3}, j={6,7}
        BF8 pf;
        pf.w[0] = rlo.x; pf.w[1] = rhi.x; pf.w[2] = rlo.y; pf.w[3] = rhi.y;
        BF8 v0, v1;
        v0.u = *(const u16x8*)(VsB + rb + cx[kt * 2 + s]);
        v1.u = *(const u16x8*)(VsB + 4096 + rb + cx[kt * 2 + s]);
        __builtin_amdgcn_s_setprio(1);
        oa0 = __builtin_amdgcn_mfma_f32_32x32x16_bf16(v0.b, pf.b, oa0, 0, 0, 0);
        oa1 = __builtin_amdgcn_mfma_f32_32x32x16_bf16(v1.b, pf.b, oa1, 0, 0, 0);
        __builtin_amdgcn_s_setprio(0);
      }
    }
    __syncthreads();   // drains vmcnt; guards Ks/Vs buffer flip
  }

  // ---- epilogue: l = own-half + other-half; O[q][d] = O^T[d][q] / l ----
  {
    float lo2 = __shfl_xor(ls, 32);
    float inv = 1.0f / (ls + lo2);
    float* op = O + hbase + (size_t)(q0 + l31) * D_DIM;
    #pragma unroll
    for (int dt = 0; dt < 2; ++dt) {
      const f32x16 oa = dt ? oa1 : oa0;
      #pragma unroll
      for (int b2 = 0; b2 < 4; ++b2) {
        f32x4 vv;
        vv[0] = oa[4 * b2 + 0] * inv;
        vv[1] = oa[4 * b2 + 1] * inv;
        vv[2] = oa[4 * b2 + 2] * inv;
        vv[3] = oa[4 * b2 + 3] * inv;
        *(f32x4*)(op + dt * 32 + b2 * 8 + h * 4) = vv;
      }
    }
  }
}

extern "C" void kernel_launch(void* const* d_in, const int* in_sizes, int n_in,
                              void* d_out, int out_size, void* d_ws, size_t ws_size,
                              hipStream_t stream) {
  const float* q = (const float*)d_in[0];
  const float* k = (const float*)d_in[1];
  const float* v = (const float*)d_in[2];
  float* o = (float*)d_out;
  unsigned short* kb = (unsigned short*)d_ws;
  unsigned short* vt = kb + (size_t)BH_TOTAL * S_LEN * D_DIM;

  cvt_k<<<dim3(4096), 256, 0, stream>>>(k, kb);
  tr_v<<<dim3(2048), 256, 0, stream>>>(v, vt);
  attn_fwd<<<dim3(1024), 256, 0, stream>>>(q, kb, vt, o);
}